// Round 10
// baseline (1063.800 us; speedup 1.0000x reference)
//
#include <hip/hip_runtime.h>
#include <hip/hip_bf16.h>
#include <math.h>

// ---------------- static problem config ----------------
#define NKEYS 13294
#define BATCH 2
#define MROWS (BATCH * NKEYS)   // 26588
#define EDIM  256
#define FDIM  1024
#define EPSV  1e-5f

typedef __bf16 bf16x8 __attribute__((ext_vector_type(8)));
typedef float  f32x4  __attribute__((ext_vector_type(4)));
typedef float  f32x2  __attribute__((ext_vector_type(2)));

__device__ __forceinline__ void async16(const void* g, void* l) {
    __builtin_amdgcn_global_load_lds(
        (const __attribute__((address_space(1))) void*)g,
        (__attribute__((address_space(3))) void*)l, 16, 0, 0);
}

// ---------------- bf16 MFMA GEMM (BM=128 x BN=128, waves 2x2 of 64x64, dbuf) ----------------
// R18: OPERAND-SWAPPED mfma(b, a, acc) -> C mapping row=lane&15, col=quad*4+r.
// All stores are 8-B uint2 packs. XCD swizzle kept.
// MODE 1: split fused store (N=640): col<256 -> v_bf head-major bf16;
//         col<512 -> o_off bf16 (stride 256); aw tile (bn==512) -> R23 fused
//         softmax (f32 logits, 2 shfl_xor over quad) -> normalized bf16 o_aw.
// MODE 3: bf16 out + ReLU (stride N).
// R19/R20 lesson: fused FFN loses to this split pair. FFN stays split.
// NOTE (R24): staging LDS dest is w*512 + lane*8 elems = wave-uniform + lane*16B
// — the ONLY dest pattern global_load_lds supports (m104). Do not re-tile it.
template<int MODE>
__global__ __launch_bounds__(256, 4) void gemm_mfma_k(
    const __hip_bfloat16* __restrict__ A, const __hip_bfloat16* __restrict__ WT,
    const float* __restrict__ bias, __hip_bfloat16* __restrict__ Cout,
    int M, int N, int K,
    __hip_bfloat16* __restrict__ o_vb, __hip_bfloat16* __restrict__ o_off,
    __hip_bfloat16* __restrict__ o_aw)
{
    constexpr int BM = 128, BN = 128, BKc = 32;
    constexpr int SMX = (BM + BN) * BKc;           // 8192 elems = 16 KB / buffer
    __shared__ __hip_bfloat16 smem[2 * SMX];       // 32 KB

    // ---- XCD-aware tile swizzle ----
    const int gx = gridDim.x, nb = gx * gridDim.y;
    int bxi = blockIdx.x, byi = blockIdx.y;
    if ((nb & 7) == 0) {
        const int id   = byi * gx + bxi;
        const int tile = (id & 7) * (nb >> 3) + (id >> 3);
        bxi = tile % gx; byi = tile / gx;
    }
    const int bm = byi * BM;
    const int bn = bxi * BN;

    const int tid  = threadIdx.x;
    const int lane = tid & 63;
    const int w    = tid >> 6;
    const int wr   = w >> 1, wc = w & 1;           // wave grid 2x2, tile 64x64
    const int l15  = lane & 15, quad = lane >> 4;

    const int gRow = tid >> 2;
    const int kc8  = (tid & 3) * 8;
    const __hip_bfloat16* gsrc[4];
    int ldsoff[4];
    #pragma unroll
    for (int rr = 0; rr < 4; ++rr) {
        const int gr = gRow + 64 * rr;             // 0..255
        if (gr < BM) {
            int ar = bm + gr; if (ar >= M) ar = M - 1;
            gsrc[rr] = A + (size_t)ar * K + kc8;
        } else {
            gsrc[rr] = WT + (size_t)(bn + gr - BM) * K + kc8;
        }
        ldsoff[rr] = gr * BKc + kc8;               // = wave_base + lane*8 elems
    }

    f32x4 acc[4][4];
    #pragma unroll
    for (int i = 0; i < 4; ++i)
        #pragma unroll
        for (int j = 0; j < 4; ++j) acc[i][j] = (f32x4)0.f;

    const int T = K / BKc;
    #pragma unroll
    for (int rr = 0; rr < 4; ++rr) async16(gsrc[rr], smem + ldsoff[rr]);

    for (int it = 0; it < T; ++it) {
        __syncthreads();
        if (it + 1 < T) {
            const int nxt = ((it + 1) & 1) * SMX;
            const int ko  = (it + 1) * BKc;
            #pragma unroll
            for (int rr = 0; rr < 4; ++rr) async16(gsrc[rr] + ko, smem + nxt + ldsoff[rr]);
        }
        const __hip_bfloat16* sA = smem + (it & 1) * SMX;
        const __hip_bfloat16* sB = sA + BM * BKc;

        bf16x8 a[4], b[4];
        #pragma unroll
        for (int mt = 0; mt < 4; ++mt)
            a[mt] = *(const bf16x8*)&sA[(wr * 64 + mt * 16 + l15) * BKc + quad * 8];
        #pragma unroll
        for (int nt = 0; nt < 4; ++nt)
            b[nt] = *(const bf16x8*)&sB[(wc * 64 + nt * 16 + l15) * BKc + quad * 8];
        #pragma unroll
        for (int mt = 0; mt < 4; ++mt)
            #pragma unroll
            for (int nt = 0; nt < 4; ++nt)
                acc[mt][nt] = __builtin_amdgcn_mfma_f32_16x16x32_bf16(
                    b[nt], a[mt], acc[mt][nt], 0, 0, 0);   // swapped: row=l15, col=quad*4+r
    }

    // ---- R23: aw tile -> fused softmax epilogue ----
    // 16 logits of (row, head h=wc*4+nt) live in cols {quad*4+r}; row = l15-indexed,
    // quad-invariant -> shfl_xor(16,32) reduce over quads is exact. f32 softmax.
    if (MODE == 1 && bn == 512) {
        #pragma unroll
        for (int nt = 0; nt < 4; ++nt) {
            const int col = 512 + wc * 64 + nt * 16 + quad * 4;
            const float4 bz = *(const float4*)&bias[col];
            #pragma unroll
            for (int mt = 0; mt < 4; ++mt) {
                const int row = bm + wr * 64 + mt * 16 + l15;
                const float v0 = acc[mt][nt][0] + bz.x;
                const float v1 = acc[mt][nt][1] + bz.y;
                const float v2 = acc[mt][nt][2] + bz.z;
                const float v3 = acc[mt][nt][3] + bz.w;
                float mx = fmaxf(fmaxf(v0, v1), fmaxf(v2, v3));
                mx = fmaxf(mx, __shfl_xor(mx, 16, 64));
                mx = fmaxf(mx, __shfl_xor(mx, 32, 64));
                const float e0 = __expf(v0 - mx), e1 = __expf(v1 - mx);
                const float e2 = __expf(v2 - mx), e3 = __expf(v3 - mx);
                float s = e0 + e1 + e2 + e3;
                s += __shfl_xor(s, 16, 64);
                s += __shfl_xor(s, 32, 64);
                const float rs = 1.f / s;
                if (row < M) {
                    union { uint2 u; __hip_bfloat16 h[4]; } p;
                    p.h[0] = __float2bfloat16(e0 * rs);
                    p.h[1] = __float2bfloat16(e1 * rs);
                    p.h[2] = __float2bfloat16(e2 * rs);
                    p.h[3] = __float2bfloat16(e3 * rs);
                    *(uint2*)&o_aw[(size_t)row * 128 + (col - 512)] = p.u;
                }
            }
        }
        return;
    }

    // epilogue: row = bm+wr*64+mt*16+l15 ; col = bn+wc*64+nt*16+quad*4+{0..3}
    #pragma unroll
    for (int nt = 0; nt < 4; ++nt) {
        const int col = bn + wc * 64 + nt * 16 + quad * 4;
        const float4 bz = *(const float4*)&bias[col];
        #pragma unroll
        for (int mt = 0; mt < 4; ++mt) {
            const int row = bm + wr * 64 + mt * 16 + l15;
            if (row >= M) continue;
            float v0 = acc[mt][nt][0] + bz.x;
            float v1 = acc[mt][nt][1] + bz.y;
            float v2 = acc[mt][nt][2] + bz.z;
            float v3 = acc[mt][nt][3] + bz.w;
            if (MODE == 3) {
                v0 = fmaxf(v0, 0.f); v1 = fmaxf(v1, 0.f);
                v2 = fmaxf(v2, 0.f); v3 = fmaxf(v3, 0.f);
            }
            union { uint2 u; __hip_bfloat16 h[4]; } p;
            p.h[0] = __float2bfloat16(v0); p.h[1] = __float2bfloat16(v1);
            p.h[2] = __float2bfloat16(v2); p.h[3] = __float2bfloat16(v3);
            if (MODE == 1) {
                if (col < 256) {
                    const int bb = (row >= NKEYS) ? 1 : 0;
                    const int hh = col >> 5, d = col & 31;
                    // row already contains +NKEYS for bb=1, hence bb*7
                    *(uint2*)&o_vb[((size_t)(bb * 7 + hh) * NKEYS + row) * 32 + d] = p.u;
                } else {
                    *(uint2*)&o_off[(size_t)row * 256 + (col - 256)] = p.u;
                }
            } else {
                *(uint2*)&Cout[(size_t)row * N + col] = p.u;
            }
        }
    }
}

// ---------------- fused GEMM + residual(bf16) + LayerNorm ----------------
// R24: 8 waves / 512 threads, 64x256 tile (wave grid 2x4, per-wave 32x64,
// acc[2][4]); R21 slab structure (64 K per barrier). STAGING FIX vs R23:
// LDS dest = idx*8 elems with idx = rr*512+tid -> within a wave consecutive
// in lane = wave-uniform base + lane*16B, the only pattern global_load_lds
// supports (m104 — R23's scattered dest silently wrote wrong LDS -> NaN).
// Source (slab,row,kc) decomposed from idx; per-lane global addr is allowed.
// __launch_bounds__(512,4): VGPR cap 128 so LDS (80KB, 2 blocks/CU) binds.
template<int FINAL>
__global__ __launch_bounds__(512, 4) void gemm_ln_k(
    const __hip_bfloat16* __restrict__ A, const __hip_bfloat16* __restrict__ WT,
    const float* __restrict__ bias, const __hip_bfloat16* __restrict__ xres,
    const float* __restrict__ g, const float* __restrict__ bta,
    float* __restrict__ xfout, __hip_bfloat16* __restrict__ xbout,
    int M, int K)
{
    constexpr int BM = 64, BN = 256, BKc = 32;
    constexpr int ROWS = BM + BN;          // 320
    constexpr int SLAB = ROWS * BKc;       // 10240 elems = 20 KB
    constexpr int SMX  = 2 * SLAB;         // 40 KB / buffer (two K-slabs)
    __shared__ __hip_bfloat16 smem[2 * SMX];  // 80 KB

    const int tid  = threadIdx.x;          // 0..511
    const int bm   = blockIdx.x * BM;
    const int lane = tid & 63;
    const int w    = tid >> 6;             // 0..7
    const int wr   = w >> 2;               // 0..1 (row half)
    const int wc   = w & 3;                // 0..3 (col quarter)
    const int l15  = lane & 15, quad = lane >> 4;

    // ---- staging: idx = rr*512+tid; LDS dest = idx*8 elems (lane-contiguous) ----
    const __hip_bfloat16* gsrc[5];
    int ldsoff[5];
    #pragma unroll
    for (int rr = 0; rr < 5; ++rr) {
        const int idx = rr * 512 + tid;    // 0..2559
        const int rG  = idx >> 2;          // global row 0..639 (2 slabs x 320)
        const int kcc = (idx & 3) * 8;     // elem offset within 32-elem slab row
        const int sl  = (rG >= 320) ? 1 : 0;
        const int gr  = rG - sl * 320;     // row within slab, 0..319
        if (gr < BM) {
            int ar = bm + gr; if (ar >= M) ar = M - 1;
            gsrc[rr] = A + (size_t)ar * K + sl * 32 + kcc;
        } else {
            gsrc[rr] = WT + (size_t)(gr - BM) * K + sl * 32 + kcc;
        }
        ldsoff[rr] = idx * 8;              // == sl*SLAB + gr*32 + kcc
    }

    f32x4 acc[2][4];
    #pragma unroll
    for (int i = 0; i < 2; ++i)
        #pragma unroll
        for (int j = 0; j < 4; ++j) acc[i][j] = (f32x4)0.f;

    const int T = K / 64;                  // 64 K-elems per iteration
    #pragma unroll
    for (int rr = 0; rr < 5; ++rr) async16(gsrc[rr], smem + ldsoff[rr]);

    for (int it = 0; it < T; ++it) {
        __syncthreads();
        if (it + 1 < T) {
            const int nxt = ((it + 1) & 1) * SMX;
            const int ko  = (it + 1) * 64;
            #pragma unroll
            for (int rr = 0; rr < 5; ++rr)
                async16(gsrc[rr] + ko, smem + nxt + ldsoff[rr]);
        }
        #pragma unroll
        for (int s = 0; s < 2; ++s) {
            const __hip_bfloat16* sA = smem + (it & 1) * SMX + s * SLAB;
            const __hip_bfloat16* sB = sA + BM * BKc;

            bf16x8 a[2], b[4];
            #pragma unroll
            for (int mt = 0; mt < 2; ++mt)
                a[mt] = *(const bf16x8*)&sA[(wr * 32 + mt * 16 + l15) * BKc + quad * 8];
            #pragma unroll
            for (int nt = 0; nt < 4; ++nt)
                b[nt] = *(const bf16x8*)&sB[(wc * 64 + nt * 16 + l15) * BKc + quad * 8];
            #pragma unroll
            for (int mt = 0; mt < 2; ++mt)
                #pragma unroll
                for (int nt = 0; nt < 4; ++nt)
                    acc[mt][nt] = __builtin_amdgcn_mfma_f32_16x16x32_bf16(
                        b[nt], a[mt], acc[mt][nt], 0, 0, 0);   // swapped
        }
    }

    const int colq = wc * 64 + quad * 4;

    // ---- residual + bias (ushort4 loads, 4 consecutive cols per lane) ----
    #pragma unroll
    for (int nt = 0; nt < 4; ++nt) {
        const int col = colq + nt * 16;
        const float4 bz = *(const float4*)&bias[col];
        #pragma unroll
        for (int mt = 0; mt < 2; ++mt) {
            int row = bm + wr * 32 + mt * 16 + l15;
            if (row >= M) row = M - 1;
            const ushort4 xr = *(const ushort4*)&xres[(size_t)row * 256 + col];
            acc[mt][nt][0] += bz.x + __uint_as_float((unsigned)xr.x << 16);
            acc[mt][nt][1] += bz.y + __uint_as_float((unsigned)xr.y << 16);
            acc[mt][nt][2] += bz.z + __uint_as_float((unsigned)xr.z << 16);
            acc[mt][nt][3] += bz.w + __uint_as_float((unsigned)xr.w << 16);
        }
    }

    __syncthreads();
    float* stats = (float*)smem;          // [4 wc][64 rows][2] = 2 KB
    #pragma unroll
    for (int mt = 0; mt < 2; ++mt) {
        float s = 0.f, sq = 0.f;
        #pragma unroll
        for (int nt = 0; nt < 4; ++nt)
            #pragma unroll
            for (int r = 0; r < 4; ++r) {
                const float v = acc[mt][nt][r];
                s += v; sq += v * v;
            }
        s  += __shfl_xor(s,  16, 64);  s  += __shfl_xor(s,  32, 64);
        sq += __shfl_xor(sq, 16, 64);  sq += __shfl_xor(sq, 32, 64);
        if (quad == 0) {
            const int rl = wr * 32 + mt * 16 + l15;
            stats[(wc * 64 + rl) * 2 + 0] = s;
            stats[(wc * 64 + rl) * 2 + 1] = sq;
        }
    }
    __syncthreads();

    #pragma unroll
    for (int mt = 0; mt < 2; ++mt) {
        const int rl  = wr * 32 + mt * 16 + l15;
        const int row = bm + rl;
        float s  = stats[rl * 2]          + stats[(64 + rl) * 2]
                 + stats[(128 + rl) * 2]  + stats[(192 + rl) * 2];
        float sq = stats[rl * 2 + 1]      + stats[(64 + rl) * 2 + 1]
                 + stats[(128 + rl) * 2 + 1] + stats[(192 + rl) * 2 + 1];
        const float mean = s * (1.f / 256.f);
        const float var  = sq * (1.f / 256.f) - mean * mean;
        const float rstd = rsqrtf(var + EPSV);
        if (row < M) {
            #pragma unroll
            for (int nt = 0; nt < 4; ++nt) {
                const int col = colq + nt * 16;
                const float4 gz  = *(const float4*)&g[col];
                const float4 bb4 = *(const float4*)&bta[col];
                const float v0 = (acc[mt][nt][0] - mean) * rstd * gz.x + bb4.x;
                const float v1 = (acc[mt][nt][1] - mean) * rstd * gz.y + bb4.y;
                const float v2 = (acc[mt][nt][2] - mean) * rstd * gz.z + bb4.z;
                const float v3 = (acc[mt][nt][3] - mean) * rstd * gz.w + bb4.w;
                union { uint2 u; __hip_bfloat16 h[4]; } p;
                p.h[0] = __float2bfloat16(v0); p.h[1] = __float2bfloat16(v1);
                p.h[2] = __float2bfloat16(v2); p.h[3] = __float2bfloat16(v3);
                *(uint2*)&xbout[(size_t)row * 256 + col] = p.u;
                if (FINAL) {
                    float4 f; f.x = v0; f.y = v1; f.z = v2; f.w = v3;
                    *(float4*)&xfout[(size_t)row * 256 + col] = f;
                }
            }
        }
    }
}

// ---------------- R22: single fused preamble kernel ----------------
#define NB_SRC  6647   // MROWS*64 float4 / 256
#define NB_WV   256
#define NB_WOFF 256
#define NB_WAW  128
#define NB_WO   256
#define NB_WF1  1024
#define NB_WF2  1024
#define NB_BIAS 3
#define NB_PREP (NB_SRC + NB_WV + NB_WOFF + NB_WAW + NB_WO + NB_WF1 + NB_WF2 + NB_BIAS)

__global__ void prep_k(
    const float* __restrict__ src,  __hip_bfloat16* __restrict__ xb,
    const float* __restrict__ Wv,   const float* __restrict__ Woff,
    const float* __restrict__ Waw,  const float* __restrict__ Wo,
    const float* __restrict__ Wf1,  const float* __restrict__ Wf2,
    const float* __restrict__ bv,   const float* __restrict__ boff,
    const float* __restrict__ baw,
    __hip_bfloat16* __restrict__ WT1, __hip_bfloat16* __restrict__ WTo,
    __hip_bfloat16* __restrict__ WTf1, __hip_bfloat16* __restrict__ WTf2,
    float* __restrict__ bias1)
{
    int b = blockIdx.x;
    const int t = threadIdx.x;

    if (b < NB_SRC) {                       // convert_src
        const int i = b * 256 + t;
        const float4 v = ((const float4*)src)[i];
        xb[i * 4 + 0] = __float2bfloat16(v.x);
        xb[i * 4 + 1] = __float2bfloat16(v.y);
        xb[i * 4 + 2] = __float2bfloat16(v.z);
        xb[i * 4 + 3] = __float2bfloat16(v.w);
        return;
    }
    b -= NB_SRC;

    const float* W; __hip_bfloat16* WT; int N, rowOff;
    if (b < NB_WV)        { W = Wv;   WT = WT1;  N = 256;  rowOff = 0;   }
    else if ((b -= NB_WV)   < NB_WOFF) { W = Woff; WT = WT1;  N = 256;  rowOff = 256; }
    else if ((b -= NB_WOFF) < NB_WAW)  { W = Waw;  WT = WT1;  N = 128;  rowOff = 512; }
    else if ((b -= NB_WAW)  < NB_WO)   { W = Wo;   WT = WTo;  N = 256;  rowOff = 0;   }
    else if ((b -= NB_WO)   < NB_WF1)  { W = Wf1;  WT = WTf1; N = 1024; rowOff = 0;   }
    else if ((b -= NB_WF1)  < NB_WF2)  { W = Wf2;  WT = WTf2; N = 256;  rowOff = 0;   }
    else {                              // pack_bias
        b -= NB_WF2;
        const int i = b * 256 + t;
        if (i < 256) bias1[i] = bv[i];
        else if (i < 512) bias1[i] = boff[i - 256];
        else if (i < 640) bias1[i] = baw[i - 512];
        return;
    }
    const int idx = b * 256 + t;
    const int k = idx / N, n = idx % N;
    const int K = (WT == WTf2) ? 1024 : 256;
    WT[(size_t)(rowOff + n) * K + k] = __float2bfloat16(W[idx]);
}

// ---------------- deformable-attention sampling: R13 structure + R23 softmax hoist ----------------
// Gather/FMA structure untouched (proven local optimum: full unroll, 4
// independent gathers/iter, VGPR 32, 0 conflicts). aw arrives PRE-SOFTMAXED
// from gemm_mfma<1>'s epilogue -> phase 1 drops 8 shuffles + exp + div.
__global__ __launch_bounds__(256) void sample_k(
    const __hip_bfloat16* __restrict__ v_bf, // (B*8, NKEYS, 32) bf16 head-major
    const __hip_bfloat16* __restrict__ offb, // (M,256) bf16
    const __hip_bfloat16* __restrict__ awb,  // (M,128) bf16, normalized
    const float* __restrict__ ref,           // (M,4,2)
    __hip_bfloat16* __restrict__ out)        // (M,256)
{
    __shared__ alignas(16) float sw[272][4];
    __shared__ alignas(16) int   sa[272][4];
    const int t  = threadIdx.x;
    const int q0 = blockIdx.x * 2;
    const int qi = t >> 7, h = (t >> 4) & 7;

    // ---- phase 1: (qi, h, i) ----
    {
        const int i = t & 15;
        const int q = q0 + qi;
        const int l = i >> 2;
        const float aw = __bfloat162float(awb[(size_t)q * 128 + h * 16 + i]);  // pre-softmaxed

        const int ww = (l == 0) ? 100 : (l == 1) ? 50 : (l == 2) ? 25 : 13;
        const int ls = (l == 0) ? 0 : (l == 1) ? 10000 : (l == 2) ? 12500 : 13125;
        const int b  = (q >= NKEYS) ? 1 : 0;
        const int slab = (b * 8 + h) * NKEYS + ls;

        const __hip_bfloat162 ofp = *(const __hip_bfloat162*)&offb[(size_t)q * 256 + h * 32 + i * 2];
        const float2 rf = *(const float2*)&ref[(size_t)q * 8 + l * 2];
        const float x = rf.x * (float)ww + __bfloat162float(ofp.x) - 0.5f;
        const float y = rf.y * (float)ww + __bfloat162float(ofp.y) - 0.5f;  // ww==hh per level
        const float x0f = floorf(x), y0f = floorf(y);
        const float lx = x - x0f, ly = y - y0f;
        const int x0 = (int)x0f, y0 = (int)y0f;
        const bool x0ok = (x0 >= 0) & (x0 < ww);
        const bool x1ok = (x0 + 1 >= 0) & (x0 + 1 < ww);
        const bool y0ok = (y0 >= 0) & (y0 < ww);
        const bool y1ok = (y0 + 1 >= 0) & (y0 + 1 < ww);

        float w00 = (1.f - lx) * (1.f - ly) * aw;
        float w01 = lx * (1.f - ly) * aw;
        float w10 = (1.f - lx) * ly * aw;
        float w11 = lx * ly * aw;
        int a00 = slab + y0 * ww + x0;
        int a01 = a00 + 1;
        int a10 = a00 + ww;
        int a11 = a10 + 1;
        if (!(y0ok & x0ok)) { w00 = 0.f; a00 = 0; }
        if (!(y0ok & x1ok)) { w01 = 0.f; a01 = 0; }
        if (!(y1ok & x0ok)) { w10 = 0.f; a10 = 0; }
        if (!(y1ok & x1ok)) { w11 = 0.f; a11 = 0; }

        const int idx = (qi * 8 + h) * 17 + i;
        sw[idx][0] = w00; sw[idx][1] = w01; sw[idx][2] = w10; sw[idx][3] = w11;
        sa[idx][0] = a00 * 64; sa[idx][1] = a01 * 64;   // byte offsets (row = 64 B)
        sa[idx][2] = a10 * 64; sa[idx][3] = a11 * 64;
    }
    __syncthreads();

    // ---- phase 2: (qi, h, dim-pair d2) ----
    const int d2 = t & 15;
    const unsigned d4 = d2 * 4;
    const char* vb = (const char*)v_bf;
    const int ebase = (qi * 8 + h) * 17;
    f32x2 acc = (f32x2)0.f;
    #pragma unroll
    for (int i = 0; i < 16; ++i) {
        const f32x4 wv = *(const f32x4*)sw[ebase + i];
        const int4  av = *(const int4*)sa[ebase + i];
        const unsigned p0 = *(const unsigned*)(vb + ((unsigned)av.x + d4));
        const unsigned p1 = *(const unsigned*)(vb + ((unsigned)av.y + d4));
        const unsigned p2 = *(const unsigned*)(vb + ((unsigned)av.z + d4));
        const unsigned p3 = *(const unsigned*)(vb + ((unsigned)av.w + d4));
        f32x2 v;
        v[0] = __uint_as_float(p0 << 16); v[1] = __uint_as_float(p0 & 0xffff0000u);
        acc += (f32x2)(wv[0]) * v;
        v[0] = __uint_as_float(p1 << 16); v[1] = __uint_as_float(p1 & 0xffff0000u);
        acc += (f32x2)(wv[1]) * v;
        v[0] = __uint_as_float(p2 << 16); v[1] = __uint_as_float(p2 & 0xffff0000u);
        acc += (f32x2)(wv[2]) * v;
        v[0] = __uint_as_float(p3 << 16); v[1] = __uint_as_float(p3 & 0xffff0000u);
        acc += (f32x2)(wv[3]) * v;
    }
    __hip_bfloat162 ov;
    ov.x = __float2bfloat16(acc[0]);
    ov.y = __float2bfloat16(acc[1]);
    *(__hip_bfloat162*)&out[(size_t)(q0 + qi) * 256 + h * 32 + d2 * 2] = ov;
}

// ---------------- host ----------------
extern "C" void kernel_launch(void* const* d_in, const int* in_sizes, int n_in,
                              void* d_out, int out_size, void* d_ws, size_t ws_size,
                              hipStream_t stream)
{
    const float* src  = (const float*)d_in[0];
    const float* ref  = (const float*)d_in[1];
    const float* Woff = (const float*)d_in[4];
    const float* boff = (const float*)d_in[5];
    const float* Waw  = (const float*)d_in[6];
    const float* baw  = (const float*)d_in[7];
    const float* Wv   = (const float*)d_in[8];
    const float* bv   = (const float*)d_in[9];
    const float* Wo   = (const float*)d_in[10];
    const float* bo   = (const float*)d_in[11];
    const float* ln1g = (const float*)d_in[12];
    const float* ln1b = (const float*)d_in[13];
    const float* Wf1  = (const float*)d_in[14];
    const float* bf1  = (const float*)d_in[15];
    const float* Wf2  = (const float*)d_in[16];
    const float* bf2  = (const float*)d_in[17];
    const float* ln2g = (const float*)d_in[18];
    const float* ln2b = (const float*)d_in[19];

    float* x = (float*)d_out;

    float* ws = (float*)d_ws;
    float* bias1 = ws;                                    // 640 f32
    __hip_bfloat16* v_bf  = (__hip_bfloat16*)(bias1 + 640);
    __hip_bfloat16* offb  = v_bf  + (size_t)MROWS * 256;
    __hip_bfloat16* awb   = offb  + (size_t)MROWS * 256;
    __hip_bfloat16* xb    = awb   + (size_t)MROWS * 128;
    __hip_bfloat16* attnb = xb    + (size_t)MROWS * 256;
    __hip_bfloat16* hb    = attnb + (size_t)MROWS * 256;
    __hip_bfloat16* WT1   = hb    + (size_t)MROWS * 1024;
    __hip_bfloat16* WTo   = WT1   + 640 * 256;
    __hip_bfloat16* WTf1  = WTo   + 256 * 256;
    __hip_bfloat16* WTf2  = WTf1  + 1024 * 256;

    prep_k<<<NB_PREP, 256, 0, stream>>>(
        src, xb, Wv, Woff, Waw, Wo, Wf1, Wf2, bv, boff, baw,
        WT1, WTo, WTf1, WTf2, bias1);

    const int gy  = (MROWS + 127) / 128;  // 208
    const int gln = (MROWS + 63) / 64;    // 416
    for (int layer = 0; layer < 6; ++layer) {
        gemm_mfma_k<1><<<dim3(640 / 128, gy), 256, 0, stream>>>(
            xb, WT1, bias1, nullptr, MROWS, 640, 256, v_bf, offb, awb);
        sample_k<<<MROWS / 2, 256, 0, stream>>>(v_bf, offb, awb, ref, attnb);
        gemm_ln_k<0><<<gln, 512, 0, stream>>>(
            attnb, WTo, bo, xb, ln1g, ln1b, nullptr, xb, MROWS, 256);
        gemm_mfma_k<3><<<dim3(1024 / 128, gy), 256, 0, stream>>>(
            xb, WTf1, bf1, hb, MROWS, 1024, 256, nullptr, nullptr, nullptr);
        if (layer < 5)
            gemm_ln_k<0><<<gln, 512, 0, stream>>>(
                hb, WTf2, bf2, xb, ln2g, ln2b, nullptr, xb, MROWS, 1024);
        else
            gemm_ln_k<1><<<gln, 512, 0, stream>>>(
                hb, WTf2, bf2, xb, ln2g, ln2b, x, xb, MROWS, 1024);
    }
}

// Round 11
// 975.372 us; speedup vs baseline: 1.0907x; 1.0907x over previous
//
#include <hip/hip_runtime.h>
#include <hip/hip_bf16.h>
#include <math.h>

// ---------------- static problem config ----------------
#define NKEYS 13294
#define BATCH 2
#define MROWS (BATCH * NKEYS)   // 26588
#define EDIM  256
#define FDIM  1024
#define EPSV  1e-5f

typedef __bf16 bf16x8 __attribute__((ext_vector_type(8)));
typedef float  f32x4  __attribute__((ext_vector_type(4)));
typedef float  f32x2  __attribute__((ext_vector_type(2)));

__device__ __forceinline__ void async16(const void* g, void* l) {
    __builtin_amdgcn_global_load_lds(
        (const __attribute__((address_space(1))) void*)g,
        (__attribute__((address_space(3))) void*)l, 16, 0, 0);
}

// ---------------- bf16 MFMA GEMM (BM=128 x BN=128, waves 2x2 of 64x64, dbuf) ----------------
// R18: OPERAND-SWAPPED mfma(b, a, acc) -> C mapping row=lane&15, col=quad*4+r.
// All stores are 8-B uint2 packs. XCD swizzle kept.
// MODE 1: split fused store (N=640): col<256 -> v_bf head-major bf16;
//         col<512 -> o_off bf16 (stride 256); else -> o_aw bf16 (stride 128).
// MODE 3: bf16 out + ReLU (stride N).
// R19/R20: fused FFN loses to this split pair. R24: softmax hoist into the aw
// epilogue was NET-NEGATIVE (sample_k is phase-2-bound; hoist only added cost
// here). R21 lesson: barrier-halving not ported here (drains already hidden at
// 4+ blocks/CU). T2 swizzle for the 1.7M LDS conflicts: NULL on this 2-phase
// structure per regime gate — needs full 8-phase rewrite to pay.
template<int MODE>
__global__ __launch_bounds__(256, 4) void gemm_mfma_k(
    const __hip_bfloat16* __restrict__ A, const __hip_bfloat16* __restrict__ WT,
    const float* __restrict__ bias, __hip_bfloat16* __restrict__ Cout,
    int M, int N, int K,
    __hip_bfloat16* __restrict__ o_vb, __hip_bfloat16* __restrict__ o_off,
    __hip_bfloat16* __restrict__ o_aw)
{
    constexpr int BM = 128, BN = 128, BKc = 32;
    constexpr int SMX = (BM + BN) * BKc;           // 8192 elems = 16 KB / buffer
    __shared__ __hip_bfloat16 smem[2 * SMX];       // 32 KB

    // ---- XCD-aware tile swizzle ----
    const int gx = gridDim.x, nb = gx * gridDim.y;
    int bxi = blockIdx.x, byi = blockIdx.y;
    if ((nb & 7) == 0) {
        const int id   = byi * gx + bxi;
        const int tile = (id & 7) * (nb >> 3) + (id >> 3);
        bxi = tile % gx; byi = tile / gx;
    }
    const int bm = byi * BM;
    const int bn = bxi * BN;

    const int tid  = threadIdx.x;
    const int lane = tid & 63;
    const int w    = tid >> 6;
    const int wr   = w >> 1, wc = w & 1;           // wave grid 2x2, tile 64x64
    const int l15  = lane & 15, quad = lane >> 4;

    const int gRow = tid >> 2;
    const int kc8  = (tid & 3) * 8;
    const __hip_bfloat16* gsrc[4];
    int ldsoff[4];
    #pragma unroll
    for (int rr = 0; rr < 4; ++rr) {
        const int gr = gRow + 64 * rr;             // 0..255
        if (gr < BM) {
            int ar = bm + gr; if (ar >= M) ar = M - 1;
            gsrc[rr] = A + (size_t)ar * K + kc8;
        } else {
            gsrc[rr] = WT + (size_t)(bn + gr - BM) * K + kc8;
        }
        ldsoff[rr] = gr * BKc + kc8;               // = wave_base + lane*8 elems
    }

    f32x4 acc[4][4];
    #pragma unroll
    for (int i = 0; i < 4; ++i)
        #pragma unroll
        for (int j = 0; j < 4; ++j) acc[i][j] = (f32x4)0.f;

    const int T = K / BKc;
    #pragma unroll
    for (int rr = 0; rr < 4; ++rr) async16(gsrc[rr], smem + ldsoff[rr]);

    for (int it = 0; it < T; ++it) {
        __syncthreads();
        if (it + 1 < T) {
            const int nxt = ((it + 1) & 1) * SMX;
            const int ko  = (it + 1) * BKc;
            #pragma unroll
            for (int rr = 0; rr < 4; ++rr) async16(gsrc[rr] + ko, smem + nxt + ldsoff[rr]);
        }
        const __hip_bfloat16* sA = smem + (it & 1) * SMX;
        const __hip_bfloat16* sB = sA + BM * BKc;

        bf16x8 a[4], b[4];
        #pragma unroll
        for (int mt = 0; mt < 4; ++mt)
            a[mt] = *(const bf16x8*)&sA[(wr * 64 + mt * 16 + l15) * BKc + quad * 8];
        #pragma unroll
        for (int nt = 0; nt < 4; ++nt)
            b[nt] = *(const bf16x8*)&sB[(wc * 64 + nt * 16 + l15) * BKc + quad * 8];
        #pragma unroll
        for (int mt = 0; mt < 4; ++mt)
            #pragma unroll
            for (int nt = 0; nt < 4; ++nt)
                acc[mt][nt] = __builtin_amdgcn_mfma_f32_16x16x32_bf16(
                    b[nt], a[mt], acc[mt][nt], 0, 0, 0);   // swapped: row=l15, col=quad*4+r
    }

    // epilogue: row = bm+wr*64+mt*16+l15 ; col = bn+wc*64+nt*16+quad*4+{0..3}
    #pragma unroll
    for (int nt = 0; nt < 4; ++nt) {
        const int col = bn + wc * 64 + nt * 16 + quad * 4;
        const float4 bz = *(const float4*)&bias[col];
        #pragma unroll
        for (int mt = 0; mt < 4; ++mt) {
            const int row = bm + wr * 64 + mt * 16 + l15;
            if (row >= M) continue;
            float v0 = acc[mt][nt][0] + bz.x;
            float v1 = acc[mt][nt][1] + bz.y;
            float v2 = acc[mt][nt][2] + bz.z;
            float v3 = acc[mt][nt][3] + bz.w;
            if (MODE == 3) {
                v0 = fmaxf(v0, 0.f); v1 = fmaxf(v1, 0.f);
                v2 = fmaxf(v2, 0.f); v3 = fmaxf(v3, 0.f);
            }
            union { uint2 u; __hip_bfloat16 h[4]; } p;
            p.h[0] = __float2bfloat16(v0); p.h[1] = __float2bfloat16(v1);
            p.h[2] = __float2bfloat16(v2); p.h[3] = __float2bfloat16(v3);
            if (MODE == 1) {
                if (col < 256) {
                    const int bb = (row >= NKEYS) ? 1 : 0;
                    const int hh = col >> 5, d = col & 31;
                    // row already contains +NKEYS for bb=1, hence bb*7
                    *(uint2*)&o_vb[((size_t)(bb * 7 + hh) * NKEYS + row) * 32 + d] = p.u;
                } else if (col < 512) {
                    *(uint2*)&o_off[(size_t)row * 256 + (col - 256)] = p.u;
                } else {
                    *(uint2*)&o_aw[(size_t)row * 128 + (col - 512)] = p.u;
                }
            } else {
                *(uint2*)&Cout[(size_t)row * N + col] = p.u;
            }
        }
    }
}

// ---------------- fused GEMM + residual(bf16) + LayerNorm ----------------
// BM=64 x BN=256 (full row), waves 1x4 (tile 64x64). R18 swapped layout.
// R21: 64 K-elems per barrier as TWO 32-wide slabs (one vmcnt-drain+barrier per
// 64 K). LDS 80 KB; grid 416 = 1.6 blocks/CU is the binding limit. Verified -34 us.
// R24 lesson: 512-thread/8-wave variant REGRESSED (~-45 us total) — 80 KB LDS
// still caps 2 blocks/CU, so more waves per block only raises barrier cost.
// 256 threads / 4 waves is the verified optimum for this structure.
template<int FINAL>
__global__ __launch_bounds__(256, 2) void gemm_ln_k(
    const __hip_bfloat16* __restrict__ A, const __hip_bfloat16* __restrict__ WT,
    const float* __restrict__ bias, const __hip_bfloat16* __restrict__ xres,
    const float* __restrict__ g, const float* __restrict__ bta,
    float* __restrict__ xfout, __hip_bfloat16* __restrict__ xbout,
    int M, int K)
{
    constexpr int BM = 64, BN = 256, BKc = 32;
    constexpr int ROWS = BM + BN;          // 320
    constexpr int SLAB = ROWS * BKc;       // 10240 elems = 20 KB
    constexpr int SMX  = 2 * SLAB;         // 40 KB / buffer (two K-slabs)
    __shared__ __hip_bfloat16 smem[2 * SMX];  // 80 KB

    const int tid  = threadIdx.x;
    const int bm   = blockIdx.x * BM;
    const int lane = tid & 63;
    const int w    = tid >> 6;
    const int l15  = lane & 15, quad = lane >> 4;

    const int gRow = tid >> 2;
    const int kc8  = (tid & 3) * 8;
    const __hip_bfloat16* gsrc[5];
    int ldsoff[5];
    #pragma unroll
    for (int rr = 0; rr < 5; ++rr) {
        const int gr = gRow + 64 * rr;     // 0..319
        if (gr < BM) {
            int ar = bm + gr; if (ar >= M) ar = M - 1;
            gsrc[rr] = A + (size_t)ar * K + kc8;
        } else {
            gsrc[rr] = WT + (size_t)(gr - BM) * K + kc8;
        }
        ldsoff[rr] = gr * BKc + kc8;
    }

    f32x4 acc[4][4];
    #pragma unroll
    for (int i = 0; i < 4; ++i)
        #pragma unroll
        for (int j = 0; j < 4; ++j) acc[i][j] = (f32x4)0.f;

    const int T = K / 64;                  // 64 K-elems per iteration
    #pragma unroll
    for (int rr = 0; rr < 5; ++rr) {
        async16(gsrc[rr],      smem + ldsoff[rr]);
        async16(gsrc[rr] + 32, smem + SLAB + ldsoff[rr]);
    }

    for (int it = 0; it < T; ++it) {
        __syncthreads();
        if (it + 1 < T) {
            const int nxt = ((it + 1) & 1) * SMX;
            const int ko  = (it + 1) * 64;
            #pragma unroll
            for (int rr = 0; rr < 5; ++rr) {
                async16(gsrc[rr] + ko,      smem + nxt + ldsoff[rr]);
                async16(gsrc[rr] + ko + 32, smem + nxt + SLAB + ldsoff[rr]);
            }
        }
        #pragma unroll
        for (int s = 0; s < 2; ++s) {
            const __hip_bfloat16* sA = smem + (it & 1) * SMX + s * SLAB;
            const __hip_bfloat16* sB = sA + BM * BKc;

            bf16x8 a[4], b[4];
            #pragma unroll
            for (int mt = 0; mt < 4; ++mt)
                a[mt] = *(const bf16x8*)&sA[(mt * 16 + l15) * BKc + quad * 8];
            #pragma unroll
            for (int nt = 0; nt < 4; ++nt)
                b[nt] = *(const bf16x8*)&sB[(w * 64 + nt * 16 + l15) * BKc + quad * 8];
            #pragma unroll
            for (int mt = 0; mt < 4; ++mt)
                #pragma unroll
                for (int nt = 0; nt < 4; ++nt)
                    acc[mt][nt] = __builtin_amdgcn_mfma_f32_16x16x32_bf16(
                        b[nt], a[mt], acc[mt][nt], 0, 0, 0);   // swapped
        }
    }

    const int colq = w * 64 + quad * 4;

    // ---- residual + bias (ushort4 loads, 4 consecutive cols per lane) ----
    #pragma unroll
    for (int nt = 0; nt < 4; ++nt) {
        const int col = colq + nt * 16;
        const float4 bz = *(const float4*)&bias[col];
        #pragma unroll
        for (int mt = 0; mt < 4; ++mt) {
            int row = bm + mt * 16 + l15;
            if (row >= M) row = M - 1;
            const ushort4 xr = *(const ushort4*)&xres[(size_t)row * 256 + col];
            acc[mt][nt][0] += bz.x + __uint_as_float((unsigned)xr.x << 16);
            acc[mt][nt][1] += bz.y + __uint_as_float((unsigned)xr.y << 16);
            acc[mt][nt][2] += bz.z + __uint_as_float((unsigned)xr.z << 16);
            acc[mt][nt][3] += bz.w + __uint_as_float((unsigned)xr.w << 16);
        }
    }

    __syncthreads();
    float* stats = (float*)smem;          // [4 waves][64 rows][2]
    #pragma unroll
    for (int mt = 0; mt < 4; ++mt) {
        float s = 0.f, sq = 0.f;
        #pragma unroll
        for (int nt = 0; nt < 4; ++nt)
            #pragma unroll
            for (int r = 0; r < 4; ++r) {
                const float v = acc[mt][nt][r];
                s += v; sq += v * v;
            }
        s  += __shfl_xor(s,  16, 64);  s  += __shfl_xor(s,  32, 64);
        sq += __shfl_xor(sq, 16, 64);  sq += __shfl_xor(sq, 32, 64);
        if (quad == 0) {
            const int rl = mt * 16 + l15;
            stats[(w * 64 + rl) * 2 + 0] = s;
            stats[(w * 64 + rl) * 2 + 1] = sq;
        }
    }
    __syncthreads();

    #pragma unroll
    for (int mt = 0; mt < 4; ++mt) {
        const int rl  = mt * 16 + l15;
        const int row = bm + rl;
        float s  = stats[rl * 2]          + stats[(64 + rl) * 2]
                 + stats[(128 + rl) * 2]  + stats[(192 + rl) * 2];
        float sq = stats[rl * 2 + 1]      + stats[(64 + rl) * 2 + 1]
                 + stats[(128 + rl) * 2 + 1] + stats[(192 + rl) * 2 + 1];
        const float mean = s * (1.f / 256.f);
        const float var  = sq * (1.f / 256.f) - mean * mean;
        const float rstd = rsqrtf(var + EPSV);
        if (row < M) {
            #pragma unroll
            for (int nt = 0; nt < 4; ++nt) {
                const int col = colq + nt * 16;
                const float4 gz  = *(const float4*)&g[col];
                const float4 bb4 = *(const float4*)&bta[col];
                const float v0 = (acc[mt][nt][0] - mean) * rstd * gz.x + bb4.x;
                const float v1 = (acc[mt][nt][1] - mean) * rstd * gz.y + bb4.y;
                const float v2 = (acc[mt][nt][2] - mean) * rstd * gz.z + bb4.z;
                const float v3 = (acc[mt][nt][3] - mean) * rstd * gz.w + bb4.w;
                union { uint2 u; __hip_bfloat16 h[4]; } p;
                p.h[0] = __float2bfloat16(v0); p.h[1] = __float2bfloat16(v1);
                p.h[2] = __float2bfloat16(v2); p.h[3] = __float2bfloat16(v3);
                *(uint2*)&xbout[(size_t)row * 256 + col] = p.u;
                if (FINAL) {
                    float4 f; f.x = v0; f.y = v1; f.z = v2; f.w = v3;
                    *(float4*)&xfout[(size_t)row * 256 + col] = f;
                }
            }
        }
    }
}

// ---------------- R22: single fused preamble kernel ----------------
#define NB_SRC  6647   // MROWS*64 float4 / 256
#define NB_WV   256
#define NB_WOFF 256
#define NB_WAW  128
#define NB_WO   256
#define NB_WF1  1024
#define NB_WF2  1024
#define NB_BIAS 3
#define NB_PREP (NB_SRC + NB_WV + NB_WOFF + NB_WAW + NB_WO + NB_WF1 + NB_WF2 + NB_BIAS)

__global__ void prep_k(
    const float* __restrict__ src,  __hip_bfloat16* __restrict__ xb,
    const float* __restrict__ Wv,   const float* __restrict__ Woff,
    const float* __restrict__ Waw,  const float* __restrict__ Wo,
    const float* __restrict__ Wf1,  const float* __restrict__ Wf2,
    const float* __restrict__ bv,   const float* __restrict__ boff,
    const float* __restrict__ baw,
    __hip_bfloat16* __restrict__ WT1, __hip_bfloat16* __restrict__ WTo,
    __hip_bfloat16* __restrict__ WTf1, __hip_bfloat16* __restrict__ WTf2,
    float* __restrict__ bias1)
{
    int b = blockIdx.x;
    const int t = threadIdx.x;

    if (b < NB_SRC) {                       // convert_src
        const int i = b * 256 + t;
        const float4 v = ((const float4*)src)[i];
        xb[i * 4 + 0] = __float2bfloat16(v.x);
        xb[i * 4 + 1] = __float2bfloat16(v.y);
        xb[i * 4 + 2] = __float2bfloat16(v.z);
        xb[i * 4 + 3] = __float2bfloat16(v.w);
        return;
    }
    b -= NB_SRC;

    const float* W; __hip_bfloat16* WT; int N, rowOff;
    if (b < NB_WV)        { W = Wv;   WT = WT1;  N = 256;  rowOff = 0;   }
    else if ((b -= NB_WV)   < NB_WOFF) { W = Woff; WT = WT1;  N = 256;  rowOff = 256; }
    else if ((b -= NB_WOFF) < NB_WAW)  { W = Waw;  WT = WT1;  N = 128;  rowOff = 512; }
    else if ((b -= NB_WAW)  < NB_WO)   { W = Wo;   WT = WTo;  N = 256;  rowOff = 0;   }
    else if ((b -= NB_WO)   < NB_WF1)  { W = Wf1;  WT = WTf1; N = 1024; rowOff = 0;   }
    else if ((b -= NB_WF1)  < NB_WF2)  { W = Wf2;  WT = WTf2; N = 256;  rowOff = 0;   }
    else {                              // pack_bias
        b -= NB_WF2;
        const int i = b * 256 + t;
        if (i < 256) bias1[i] = bv[i];
        else if (i < 512) bias1[i] = boff[i - 256];
        else if (i < 640) bias1[i] = baw[i - 512];
        return;
    }
    const int idx = b * 256 + t;
    const int k = idx / N, n = idx % N;
    const int K = (WT == WTf2) ? 1024 : 256;
    WT[(size_t)(rowOff + n) * K + k] = __float2bfloat16(W[idx]);
}

// ---------------- deformable-attention sampling: R13 (proven local optimum) ----------------
// 45.2 us, VALUBusy 78%, VGPR 32, 0 bank conflicts. R15 (d8): spilled. R16 (d4):
// ILP collapse at VGPR 20. R17 (f32 rows): 2x cache footprint -> latency-bound.
// R24 (softmax hoist): sample dur UNCHANGED (phase-2-bound) — hoist reverted.
// Do not touch.
__global__ __launch_bounds__(256) void sample_k(
    const __hip_bfloat16* __restrict__ v_bf, // (B*8, NKEYS, 32) bf16 head-major
    const __hip_bfloat16* __restrict__ offb, // (M,256) bf16
    const __hip_bfloat16* __restrict__ awb,  // (M,128) bf16
    const float* __restrict__ ref,           // (M,4,2)
    __hip_bfloat16* __restrict__ out)        // (M,256)
{
    __shared__ alignas(16) float sw[272][4];
    __shared__ alignas(16) int   sa[272][4];
    const int t  = threadIdx.x;
    const int q0 = blockIdx.x * 2;
    const int qi = t >> 7, h = (t >> 4) & 7;

    // ---- phase 1: (qi, h, i) ----
    {
        const int i = t & 15;
        const int q = q0 + qi;
        const int l = i >> 2;
        const float logit = __bfloat162float(awb[(size_t)q * 128 + h * 16 + i]);
        float mx = logit;
        #pragma unroll
        for (int m = 1; m < 16; m <<= 1) mx = fmaxf(mx, __shfl_xor(mx, m, 64));
        const float e = __expf(logit - mx);
        float s = e;
        #pragma unroll
        for (int m = 1; m < 16; m <<= 1) s += __shfl_xor(s, m, 64);
        const float aw = e / s;

        const int ww = (l == 0) ? 100 : (l == 1) ? 50 : (l == 2) ? 25 : 13;
        const int ls = (l == 0) ? 0 : (l == 1) ? 10000 : (l == 2) ? 12500 : 13125;
        const int b  = (q >= NKEYS) ? 1 : 0;
        const int slab = (b * 8 + h) * NKEYS + ls;

        const __hip_bfloat162 ofp = *(const __hip_bfloat162*)&offb[(size_t)q * 256 + h * 32 + i * 2];
        const float2 rf = *(const float2*)&ref[(size_t)q * 8 + l * 2];
        const float x = rf.x * (float)ww + __bfloat162float(ofp.x) - 0.5f;
        const float y = rf.y * (float)ww + __bfloat162float(ofp.y) - 0.5f;  // ww==hh per level
        const float x0f = floorf(x), y0f = floorf(y);
        const float lx = x - x0f, ly = y - y0f;
        const int x0 = (int)x0f, y0 = (int)y0f;
        const bool x0ok = (x0 >= 0) & (x0 < ww);
        const bool x1ok = (x0 + 1 >= 0) & (x0 + 1 < ww);
        const bool y0ok = (y0 >= 0) & (y0 < ww);
        const bool y1ok = (y0 + 1 >= 0) & (y0 + 1 < ww);

        float w00 = (1.f - lx) * (1.f - ly) * aw;
        float w01 = lx * (1.f - ly) * aw;
        float w10 = (1.f - lx) * ly * aw;
        float w11 = lx * ly * aw;
        int a00 = slab + y0 * ww + x0;
        int a01 = a00 + 1;
        int a10 = a00 + ww;
        int a11 = a10 + 1;
        if (!(y0ok & x0ok)) { w00 = 0.f; a00 = 0; }
        if (!(y0ok & x1ok)) { w01 = 0.f; a01 = 0; }
        if (!(y1ok & x0ok)) { w10 = 0.f; a10 = 0; }
        if (!(y1ok & x1ok)) { w11 = 0.f; a11 = 0; }

        const int idx = (qi * 8 + h) * 17 + i;
        sw[idx][0] = w00; sw[idx][1] = w01; sw[idx][2] = w10; sw[idx][3] = w11;
        sa[idx][0] = a00 * 64; sa[idx][1] = a01 * 64;   // byte offsets (row = 64 B)
        sa[idx][2] = a10 * 64; sa[idx][3] = a11 * 64;
    }
    __syncthreads();

    // ---- phase 2: (qi, h, dim-pair d2) ----
    const int d2 = t & 15;
    const unsigned d4 = d2 * 4;
    const char* vb = (const char*)v_bf;
    const int ebase = (qi * 8 + h) * 17;
    f32x2 acc = (f32x2)0.f;
    #pragma unroll
    for (int i = 0; i < 16; ++i) {
        const f32x4 wv = *(const f32x4*)sw[ebase + i];
        const int4  av = *(const int4*)sa[ebase + i];
        const unsigned p0 = *(const unsigned*)(vb + ((unsigned)av.x + d4));
        const unsigned p1 = *(const unsigned*)(vb + ((unsigned)av.y + d4));
        const unsigned p2 = *(const unsigned*)(vb + ((unsigned)av.z + d4));
        const unsigned p3 = *(const unsigned*)(vb + ((unsigned)av.w + d4));
        f32x2 v;
        v[0] = __uint_as_float(p0 << 16); v[1] = __uint_as_float(p0 & 0xffff0000u);
        acc += (f32x2)(wv[0]) * v;
        v[0] = __uint_as_float(p1 << 16); v[1] = __uint_as_float(p1 & 0xffff0000u);
        acc += (f32x2)(wv[1]) * v;
        v[0] = __uint_as_float(p2 << 16); v[1] = __uint_as_float(p2 & 0xffff0000u);
        acc += (f32x2)(wv[2]) * v;
        v[0] = __uint_as_float(p3 << 16); v[1] = __uint_as_float(p3 & 0xffff0000u);
        acc += (f32x2)(wv[3]) * v;
    }
    __hip_bfloat162 ov;
    ov.x = __float2bfloat16(acc[0]);
    ov.y = __float2bfloat16(acc[1]);
    *(__hip_bfloat162*)&out[(size_t)(q0 + qi) * 256 + h * 32 + d2 * 2] = ov;
}

// ---------------- host ----------------
extern "C" void kernel_launch(void* const* d_in, const int* in_sizes, int n_in,
                              void* d_out, int out_size, void* d_ws, size_t ws_size,
                              hipStream_t stream)
{
    const float* src  = (const float*)d_in[0];
    const float* ref  = (const float*)d_in[1];
    const float* Woff = (const float*)d_in[4];
    const float* boff = (const float*)d_in[5];
    const float* Waw  = (const float*)d_in[6];
    const float* baw  = (const float*)d_in[7];
    const float* Wv   = (const float*)d_in[8];
    const float* bv   = (const float*)d_in[9];
    const float* Wo   = (const float*)d_in[10];
    const float* bo   = (const float*)d_in[11];
    const float* ln1g = (const float*)d_in[12];
    const float* ln1b = (const float*)d_in[13];
    const float* Wf1  = (const float*)d_in[14];
    const float* bf1  = (const float*)d_in[15];
    const float* Wf2  = (const float*)d_in[16];
    const float* bf2  = (const float*)d_in[17];
    const float* ln2g = (const float*)d_in[18];
    const float* ln2b = (const float*)d_in[19];

    float* x = (float*)d_out;

    float* ws = (float*)d_ws;
    float* bias1 = ws;                                    // 640 f32
    __hip_bfloat16* v_bf  = (__hip_bfloat16*)(bias1 + 640);
    __hip_bfloat16* offb  = v_bf  + (size_t)MROWS * 256;
    __hip_bfloat16* awb   = offb  + (size_t)MROWS * 256;
    __hip_bfloat16* xb    = awb   + (size_t)MROWS * 128;
    __hip_bfloat16* attnb = xb    + (size_t)MROWS * 256;
    __hip_bfloat16* hb    = attnb + (size_t)MROWS * 256;
    __hip_bfloat16* WT1   = hb    + (size_t)MROWS * 1024;
    __hip_bfloat16* WTo   = WT1   + 640 * 256;
    __hip_bfloat16* WTf1  = WTo   + 256 * 256;
    __hip_bfloat16* WTf2  = WTf1  + 1024 * 256;

    prep_k<<<NB_PREP, 256, 0, stream>>>(
        src, xb, Wv, Woff, Waw, Wo, Wf1, Wf2, bv, boff, baw,
        WT1, WTo, WTf1, WTf2, bias1);

    const int gy  = (MROWS + 127) / 128;  // 208
    const int gln = (MROWS + 63) / 64;    // 416
    for (int layer = 0; layer < 6; ++layer) {
        gemm_mfma_k<1><<<dim3(640 / 128, gy), 256, 0, stream>>>(
            xb, WT1, bias1, nullptr, MROWS, 640, 256, v_bf, offb, awb);
        sample_k<<<MROWS / 2, 256, 0, stream>>>(v_bf, offb, awb, ref, attnb);
        gemm_ln_k<0><<<gln, 256, 0, stream>>>(
            attnb, WTo, bo, xb, ln1g, ln1b, nullptr, xb, MROWS, 256);
        gemm_mfma_k<3><<<dim3(1024 / 128, gy), 256, 0, stream>>>(
            xb, WTf1, bf1, hb, MROWS, 1024, 256, nullptr, nullptr, nullptr);
        if (layer < 5)
            gemm_ln_k<0><<<gln, 256, 0, stream>>>(
                hb, WTf2, bf2, xb, ln2g, ln2b, nullptr, xb, MROWS, 1024);
        else
            gemm_ln_k<1><<<gln, 256, 0, stream>>>(
                hb, WTf2, bf2, xb, ln2g, ln2b, x, xb, MROWS, 1024);
    }
}